// Round 7
// baseline (344.846 us; speedup 1.0000x reference)
//
#include <hip/hip_runtime.h>

typedef __attribute__((ext_vector_type(8))) short bhalf8;
typedef __attribute__((ext_vector_type(4))) float floatx4;

#define ALPHA_LR 0.2f

__device__ __forceinline__ unsigned short f2bf(float f) {
  union { float f; unsigned int u; } v; v.f = f;
  unsigned int r = v.u + 0x7fffu + ((v.u >> 16) & 1u);
  return (unsigned short)(r >> 16);
}
__device__ __forceinline__ float bf2f(unsigned short u) {
  union { unsigned int u; float f; } v; v.u = ((unsigned int)u) << 16;
  return v.f;
}
// async global->LDS, 16B per lane; LDS dest is wave-uniform base + lane*16
__device__ __forceinline__ void gld16(const void* g, void* l) {
  __builtin_amdgcn_global_load_lds((const __attribute__((address_space(1))) unsigned int*)g,
                                   (__attribute__((address_space(3))) unsigned int*)l,
                                   16, 0, 0);
}

// ---------------------------------------------------------------------------
// k0w: W [k][n] fp32 -> WT_hi/WT_lo bf16, k-tiled layout [ks=8][n=256][k'=32].
// Also re-initializes s2maxEnc[8] (ws is re-poisoned before every call).
// ---------------------------------------------------------------------------
__global__ void k0w_split(const float* __restrict__ W,
                          unsigned short* __restrict__ WThi,
                          unsigned short* __restrict__ WTlo,
                          unsigned int* __restrict__ s2maxEnc) {
  __shared__ float s[16][17];
  const int tx = threadIdx.x, ty = threadIdx.y;
  if (blockIdx.x == 0 && blockIdx.y == 0 && ty == 0 && tx < 8) s2maxEnc[tx] = 0u;
  const int n0 = blockIdx.x * 16, k0 = blockIdx.y * 16;
  s[ty][tx] = W[(k0 + ty) * 256 + n0 + tx];
  __syncthreads();
  float v = s[tx][ty];  // = W[k0+tx][n0+ty]
  const int k = k0 + tx, n = n0 + ty;
  unsigned short hi = f2bf(v);
  unsigned short lo = f2bf(v - bf2f(hi));
  const int idx = (k >> 5) * 8192 + n * 32 + (k & 31);
  WThi[idx] = hi;
  WTlo[idx] = lo;
}

// ---------------------------------------------------------------------------
// k1: Wh = h @ W via split-bf16 MFMA (hi*hi + hi*lo + lo*hi), h split in-kernel.
// Writes WhPack bf16 [B][jt=64][f=256][j'=32], s1/s2 (fp32 dots with a), and
// per-batch encoded atomicMax of s2 (for the k3 softmax bound).
// ---------------------------------------------------------------------------
__global__ __launch_bounds__(512, 2) void k1_mfma(const float* __restrict__ h,
                                                  const unsigned short* __restrict__ Bhi_g,
                                                  const unsigned short* __restrict__ Blo_g,
                                                  const float* __restrict__ a_g,
                                                  unsigned short* __restrict__ WhPack,
                                                  float* __restrict__ s1,
                                                  float* __restrict__ s2,
                                                  unsigned int* __restrict__ s2maxEnc) {
  __shared__ unsigned short Ah[64 * 264], Al[64 * 264];  // 33 KB each
  __shared__ unsigned short Bh[2][8192], Bl[2][8192];    // 16 KB per buffer
  __shared__ float s1red[64], s2red[64];
  const int t = threadIdx.x;
  const long r0 = (long)blockIdx.x * 64;
  const int wave = t >> 6, lane = t & 63;

  if (t < 64) { s1red[t] = 0.f; s2red[t] = 0.f; }

#pragma unroll
  for (int rep = 0; rep < 2; rep++) {
    const int off = wave * 1024 + rep * 512;
    gld16(Bhi_g + off + lane * 8, &Bh[0][off]);
    gld16(Blo_g + off + lane * 8, &Bl[0][off]);
  }

#pragma unroll
  for (int q = 0; q < 8; q++) {
    int idx = q * 512 + t;
    int row = idx >> 6, c4 = idx & 63;
    float4 x = *(const float4*)(h + (r0 + row) * 256 + c4 * 4);
    float xs[4] = {x.x, x.y, x.z, x.w};
    unsigned short hs[4], ls[4];
#pragma unroll
    for (int qq = 0; qq < 4; qq++) {
      hs[qq] = f2bf(xs[qq]);
      ls[qq] = f2bf(xs[qq] - bf2f(hs[qq]));
    }
    *(ushort4*)&Ah[row * 264 + c4 * 4] = (ushort4){hs[0], hs[1], hs[2], hs[3]};
    *(ushort4*)&Al[row * 264 + c4 * 4] = (ushort4){ls[0], ls[1], ls[2], ls[3]};
  }
  __syncthreads();

  const int wm = wave >> 2, wn = wave & 3;
  const int lhi = lane >> 4, llo = lane & 15;

  floatx4 acc[2][4];
#pragma unroll
  for (int mt = 0; mt < 2; mt++)
#pragma unroll
    for (int nt = 0; nt < 4; nt++) acc[mt][nt] = (floatx4){0.f, 0.f, 0.f, 0.f};

  for (int ks = 0; ks < 8; ks++) {
    const int cur = ks & 1, nxt = cur ^ 1, ksn = (ks + 1) & 7;
#pragma unroll
    for (int rep = 0; rep < 2; rep++) {
      const int off = wave * 1024 + rep * 512;
      gld16(Bhi_g + ksn * 8192 + off + lane * 8, &Bh[nxt][off]);
      gld16(Blo_g + ksn * 8192 + off + lane * 8, &Bl[nxt][off]);
    }

    const int k0 = ks * 32;
    bhalf8 ah[2], al[2], bh[4], bl[4];
#pragma unroll
    for (int mt = 0; mt < 2; mt++) {
      int ro = (wm * 32 + mt * 16 + llo) * 264 + k0 + lhi * 8;
      ah[mt] = *(const bhalf8*)&Ah[ro];
      al[mt] = *(const bhalf8*)&Al[ro];
    }
#pragma unroll
    for (int nt = 0; nt < 4; nt++) {
      int ro = (wn * 64 + nt * 16 + llo) * 32 + lhi * 8;
      bh[nt] = *(const bhalf8*)&Bh[cur][ro];
      bl[nt] = *(const bhalf8*)&Bl[cur][ro];
    }
#pragma unroll
    for (int mt = 0; mt < 2; mt++)
#pragma unroll
      for (int nt = 0; nt < 4; nt++) {
        acc[mt][nt] = __builtin_amdgcn_mfma_f32_16x16x32_bf16(ah[mt], bh[nt], acc[mt][nt], 0, 0, 0);
        acc[mt][nt] = __builtin_amdgcn_mfma_f32_16x16x32_bf16(ah[mt], bl[nt], acc[mt][nt], 0, 0, 0);
        acc[mt][nt] = __builtin_amdgcn_mfma_f32_16x16x32_bf16(al[mt], bh[nt], acc[mt][nt], 0, 0, 0);
      }
    __syncthreads();
  }

  float a1v[4], a2v[4];
#pragma unroll
  for (int nt = 0; nt < 4; nt++) {
    int f = wn * 64 + nt * 16 + llo;
    a1v[nt] = a_g[f];
    a2v[nt] = a_g[256 + f];
  }

  const int b = (int)(r0 >> 11);
  const int jt_base = (int)((r0 & 2047) >> 5);

#pragma unroll
  for (int mt = 0; mt < 2; mt++) {
    float p1[4], p2[4];
#pragma unroll
    for (int reg = 0; reg < 4; reg++) {
      p1[reg] = acc[mt][0][reg] * a1v[0] + acc[mt][1][reg] * a1v[1] +
                acc[mt][2][reg] * a1v[2] + acc[mt][3][reg] * a1v[3];
      p2[reg] = acc[mt][0][reg] * a2v[0] + acc[mt][1][reg] * a2v[1] +
                acc[mt][2][reg] * a2v[2] + acc[mt][3][reg] * a2v[3];
    }
#pragma unroll
    for (int off = 1; off < 16; off <<= 1) {
#pragma unroll
      for (int reg = 0; reg < 4; reg++) {
        p1[reg] += __shfl_xor(p1[reg], off);
        p2[reg] += __shfl_xor(p2[reg], off);
      }
    }
    if (llo == 0) {
#pragma unroll
      for (int reg = 0; reg < 4; reg++) {
        int il = wm * 32 + mt * 16 + lhi * 4 + reg;
        atomicAdd(&s1red[il], p1[reg]);
        atomicAdd(&s2red[il], p2[reg]);
      }
    }
#pragma unroll
    for (int nt = 0; nt < 4; nt++) {
      int f = wn * 64 + nt * 16 + llo;
      int jt = jt_base + wm;
      ushort4 pk = (ushort4){f2bf(acc[mt][nt][0]), f2bf(acc[mt][nt][1]),
                             f2bf(acc[mt][nt][2]), f2bf(acc[mt][nt][3])};
      *(ushort4*)&WhPack[((long)((b * 64 + jt) * 256 + f)) * 32 + mt * 16 + lhi * 4] = pk;
    }
  }

  __syncthreads();
  if (t < 64) {
    s1[r0 + t] = s1red[t];
    s2[r0 + t] = s2red[t];
    float v = s2red[t];
#pragma unroll
    for (int o = 32; o; o >>= 1) v = fmaxf(v, __shfl_xor(v, o));
    if (t == 0) {
      unsigned int u = __float_as_uint(v);
      unsigned int key = (u & 0x80000000u) ? ~u : (u | 0x80000000u);
      atomicMax(s2maxEnc + b, key);
    }
  }
}

// ---------------------------------------------------------------------------
// K3 v4: zero in-loop LDS, zero in-loop barriers.
// A (P) built in A-frag registers: lane(llo,lhi) owns row llo, j's lhi*8..+7
// (8 exps/lane/jt). B frags straight global->VGPR (dense 1KB/instr, L1/L2-hot),
// register double-buffered. adj register-pipelined at distance 2. Denominator
// accumulated in-loop, shuffle-reduced at the end.
// Block 512 thr = 8 waves = 2 f-chunks x 4 row-groups (64 rows x 256 f).
// Grid (32 ry, 8 b) = 256 blocks. LDS: s2 stage only (8 KB).
// ---------------------------------------------------------------------------
__global__ __launch_bounds__(512, 2) void k3_attn(const unsigned short* __restrict__ WhPack,
                                                  const int* __restrict__ adj,
                                                  const float* __restrict__ s1g,
                                                  const float* __restrict__ s2g,
                                                  const unsigned int* __restrict__ s2maxEnc,
                                                  float* __restrict__ out) {
  const int t = threadIdx.x;
  const int b = blockIdx.y;
  const int wave = t >> 6, lane = t & 63;
  const int llo = lane & 15, lhi = lane >> 4;
  const int fc = wave >> 2;  // f-chunk of 128
  const int rg = wave & 3;   // row group of 16
  const long gr0 = (long)b * 2048 + blockIdx.x * 64 + rg * 16;

  __shared__ float s2all[2048];  // 8 KB
  ((float4*)s2all)[t] = ((const float4*)(s2g + (long)b * 2048))[t];

  // per-lane row constants (row = llo)
  const float s1i = s1g[gr0 + llo];
  const unsigned int ek = s2maxEnc[b];
  const float s2max = (ek & 0x80000000u) ? __uint_as_float(ek & 0x7fffffffu)
                                         : __uint_as_float(~ek);
  const float xm = s1i + s2max;
  const float Mi = fmaxf(xm, ALPHA_LR * xm);  // valid softmax shift (upper bound)

  const int* aptr = adj + (gr0 + llo) * 2048 + lhi * 8;
  const unsigned short* Bp =
      WhPack + (long)b * 64 * 8192 + (fc * 128 + llo) * 32 + lhi * 8;

  __syncthreads();  // s2all ready — the only block barrier

  floatx4 acc[8];
#pragma unroll
  for (int nt = 0; nt < 8; nt++) acc[nt] = (floatx4){0.f, 0.f, 0.f, 0.f};

  bhalf8 B0[8], B1[8];
  int4 ajq[2][2];  // adj pipeline, distance 2
  ajq[0][0] = *(const int4*)(aptr);
  ajq[0][1] = *(const int4*)(aptr + 4);
  ajq[1][0] = *(const int4*)(aptr + 32);
  ajq[1][1] = *(const int4*)(aptr + 36);
#pragma unroll
  for (int nt = 0; nt < 8; nt++) B0[nt] = *(const bhalf8*)(Bp + nt * 512);

  float lsum = 0.f;

#define K3_STEP(JT, BCUR, BNXT)                                                \
  {                                                                            \
    const int jt_ = (JT);                                                      \
    const int cb = jt_ & 1;                                                    \
    /* B prefetch for jt+1 */                                                  \
    const unsigned short* bn = Bp + ((jt_ + 1 < 64) ? jt_ + 1 : 63) * 8192;    \
    _Pragma("unroll") for (int nt = 0; nt < 8; nt++)                           \
        BNXT[nt] = *(const bhalf8*)(bn + nt * 512);                            \
    /* consume adj tile, refill at distance 2 */                               \
    int4 a0_ = ajq[cb][0], a1_ = ajq[cb][1];                                   \
    const int jp_ = (jt_ + 2 < 64) ? jt_ + 2 : 63;                             \
    ajq[cb][0] = *(const int4*)(aptr + jp_ * 32);                              \
    ajq[cb][1] = *(const int4*)(aptr + jp_ * 32 + 4);                          \
    int am_[8] = {a0_.x, a0_.y, a0_.z, a0_.w, a1_.x, a1_.y, a1_.z, a1_.w};     \
    float4 sa_ = *(const float4*)&s2all[jt_ * 32 + lhi * 8];                   \
    float4 sb_ = *(const float4*)&s2all[jt_ * 32 + lhi * 8 + 4];               \
    float sv_[8] = {sa_.x, sa_.y, sa_.z, sa_.w, sb_.x, sb_.y, sb_.z, sb_.w};   \
    union { unsigned int u[4]; bhalf8 v; } au_;                                \
    _Pragma("unroll") for (int p = 0; p < 4; p++) {                            \
      float x0 = s1i + sv_[2 * p];                                             \
      float x1 = s1i + sv_[2 * p + 1];                                         \
      x0 = fmaxf(x0, ALPHA_LR * x0);                                           \
      x1 = fmaxf(x1, ALPHA_LR * x1);                                           \
      float e0 = (am_[2 * p] > 0) ? __expf(x0 - Mi) : 0.f;                     \
      float e1 = (am_[2 * p + 1] > 0) ? __expf(x1 - Mi) : 0.f;                 \
      lsum += e0 + e1;                                                         \
      union { float f; unsigned int u; } u0_, u1_;                             \
      u0_.f = e0; u1_.f = e1;                                                  \
      au_.u[p] = (u0_.u >> 16) | (u1_.u & 0xffff0000u);                        \
    }                                                                          \
    _Pragma("unroll") for (int nt = 0; nt < 8; nt++)                           \
        acc[nt] = __builtin_amdgcn_mfma_f32_16x16x32_bf16(au_.v, BCUR[nt],     \
                                                          acc[nt], 0, 0, 0);   \
  }

  for (int jt = 0; jt < 64; jt += 2) {
    K3_STEP(jt, B0, B1)
    K3_STEP(jt + 1, B1, B0)
  }
#undef K3_STEP

  // denominator: combine the 4 lhi replicas of each row llo
  lsum += __shfl_xor(lsum, 16);
  lsum += __shfl_xor(lsum, 32);
  const float linv = 1.f / fmaxf(lsum, 1e-35f);

  // epilogue: C/D row = lhi*4+reg (need that row's linv -> shuffle), col = llo
#pragma unroll
  for (int reg = 0; reg < 4; reg++) {
    const float lr = __shfl(linv, lhi * 4 + reg);
    const int row = lhi * 4 + reg;
#pragma unroll
    for (int nt = 0; nt < 8; nt++) {
      float v = acc[nt][reg] * lr;
      v = v > 0.f ? v : expm1f(v);
      out[(gr0 + row) * 256 + fc * 128 + nt * 16 + llo] = v;
    }
  }
}

// ---------------------------------------------------------------------------
extern "C" void kernel_launch(void* const* d_in, const int* in_sizes, int n_in,
                              void* d_out, int out_size, void* d_ws, size_t ws_size,
                              hipStream_t stream) {
  const float* h = (const float*)d_in[0];
  const int* adj = (const int*)d_in[1];
  const float* W = (const float*)d_in[2];
  const float* a = (const float*)d_in[3];
  float* out = (float*)d_out;

  char* ws = (char*)d_ws;
  unsigned short* WhPack = (unsigned short*)ws;            //  8,388,608 B
  unsigned short* WThi = (unsigned short*)(ws + 8388608);  //    131,072 B
  unsigned short* WTlo = (unsigned short*)(ws + 8519680);  //    131,072 B
  float* s1 = (float*)(ws + 8650752);                      //     65,536 B
  float* s2 = (float*)(ws + 8716288);                      //     65,536 B
  unsigned int* s2maxEnc = (unsigned int*)(ws + 8781824);  //         32 B

  hipLaunchKernelGGL(k0w_split, dim3(16, 16), dim3(16, 16), 0, stream, W, WThi, WTlo, s2maxEnc);
  hipLaunchKernelGGL(k1_mfma, dim3(256), dim3(512), 0, stream, h, WThi, WTlo, a,
                     WhPack, s1, s2, s2maxEnc);
  hipLaunchKernelGGL(k3_attn, dim3(32, 8), dim3(512), 0, stream, WhPack, adj,
                     s1, s2, s2maxEnc, out);
}

// Round 8
// 311.782 us; speedup vs baseline: 1.1060x; 1.1060x over previous
//
#include <hip/hip_runtime.h>

typedef __attribute__((ext_vector_type(8))) short bhalf8;
typedef __attribute__((ext_vector_type(4))) float floatx4;

#define ALPHA_LR 0.2f

__device__ __forceinline__ unsigned short f2bf(float f) {
  union { float f; unsigned int u; } v; v.f = f;
  unsigned int r = v.u + 0x7fffu + ((v.u >> 16) & 1u);
  return (unsigned short)(r >> 16);
}
__device__ __forceinline__ float bf2f(unsigned short u) {
  union { unsigned int u; float f; } v; v.u = ((unsigned int)u) << 16;
  return v.f;
}
// async global->LDS, 16B per lane; LDS dest is wave-uniform base + lane*16,
// global src is per-lane.
__device__ __forceinline__ void gld16(const void* g, void* l) {
  __builtin_amdgcn_global_load_lds((const __attribute__((address_space(1))) unsigned int*)g,
                                   (__attribute__((address_space(3))) unsigned int*)l,
                                   16, 0, 0);
}

// ---------------------------------------------------------------------------
// k0w: W [k][n] fp32 -> WT_hi/WT_lo bf16, k-tiled layout [ks=8][n=256][k'=32].
// Also re-initializes s2maxEnc[8] (ws is re-poisoned before every call).
// ---------------------------------------------------------------------------
__global__ void k0w_split(const float* __restrict__ W,
                          unsigned short* __restrict__ WThi,
                          unsigned short* __restrict__ WTlo,
                          unsigned int* __restrict__ s2maxEnc) {
  __shared__ float s[16][17];
  const int tx = threadIdx.x, ty = threadIdx.y;
  if (blockIdx.x == 0 && blockIdx.y == 0 && ty == 0 && tx < 8) s2maxEnc[tx] = 0u;
  const int n0 = blockIdx.x * 16, k0 = blockIdx.y * 16;
  s[ty][tx] = W[(k0 + ty) * 256 + n0 + tx];
  __syncthreads();
  float v = s[tx][ty];  // = W[k0+tx][n0+ty]
  const int k = k0 + tx, n = n0 + ty;
  unsigned short hi = f2bf(v);
  unsigned short lo = f2bf(v - bf2f(hi));
  const int idx = (k >> 5) * 8192 + n * 32 + (k & 31);
  WThi[idx] = hi;
  WTlo[idx] = lo;
}

// ---------------------------------------------------------------------------
// k1: Wh = h @ W via split-bf16 MFMA (hi*hi + hi*lo + lo*hi), h split in-kernel.
// Writes WhPack bf16 [B][jt=64][f=256][j'=32], s1/s2 (fp32 dots with a), and
// per-batch encoded atomicMax of s2 (for the k3 softmax bound).
// ---------------------------------------------------------------------------
__global__ __launch_bounds__(512, 2) void k1_mfma(const float* __restrict__ h,
                                                  const unsigned short* __restrict__ Bhi_g,
                                                  const unsigned short* __restrict__ Blo_g,
                                                  const float* __restrict__ a_g,
                                                  unsigned short* __restrict__ WhPack,
                                                  float* __restrict__ s1,
                                                  float* __restrict__ s2,
                                                  unsigned int* __restrict__ s2maxEnc) {
  __shared__ unsigned short Ah[64 * 264], Al[64 * 264];  // 33 KB each
  __shared__ unsigned short Bh[2][8192], Bl[2][8192];    // 16 KB per buffer
  __shared__ float s1red[64], s2red[64];
  const int t = threadIdx.x;
  const long r0 = (long)blockIdx.x * 64;
  const int wave = t >> 6, lane = t & 63;

  if (t < 64) { s1red[t] = 0.f; s2red[t] = 0.f; }

#pragma unroll
  for (int rep = 0; rep < 2; rep++) {
    const int off = wave * 1024 + rep * 512;
    gld16(Bhi_g + off + lane * 8, &Bh[0][off]);
    gld16(Blo_g + off + lane * 8, &Bl[0][off]);
  }

#pragma unroll
  for (int q = 0; q < 8; q++) {
    int idx = q * 512 + t;
    int row = idx >> 6, c4 = idx & 63;
    float4 x = *(const float4*)(h + (r0 + row) * 256 + c4 * 4);
    float xs[4] = {x.x, x.y, x.z, x.w};
    unsigned short hs[4], ls[4];
#pragma unroll
    for (int qq = 0; qq < 4; qq++) {
      hs[qq] = f2bf(xs[qq]);
      ls[qq] = f2bf(xs[qq] - bf2f(hs[qq]));
    }
    *(ushort4*)&Ah[row * 264 + c4 * 4] = (ushort4){hs[0], hs[1], hs[2], hs[3]};
    *(ushort4*)&Al[row * 264 + c4 * 4] = (ushort4){ls[0], ls[1], ls[2], ls[3]};
  }
  __syncthreads();

  const int wm = wave >> 2, wn = wave & 3;
  const int lhi = lane >> 4, llo = lane & 15;

  floatx4 acc[2][4];
#pragma unroll
  for (int mt = 0; mt < 2; mt++)
#pragma unroll
    for (int nt = 0; nt < 4; nt++) acc[mt][nt] = (floatx4){0.f, 0.f, 0.f, 0.f};

  for (int ks = 0; ks < 8; ks++) {
    const int cur = ks & 1, nxt = cur ^ 1, ksn = (ks + 1) & 7;
#pragma unroll
    for (int rep = 0; rep < 2; rep++) {
      const int off = wave * 1024 + rep * 512;
      gld16(Bhi_g + ksn * 8192 + off + lane * 8, &Bh[nxt][off]);
      gld16(Blo_g + ksn * 8192 + off + lane * 8, &Bl[nxt][off]);
    }

    const int k0 = ks * 32;
    bhalf8 ah[2], al[2], bh[4], bl[4];
#pragma unroll
    for (int mt = 0; mt < 2; mt++) {
      int ro = (wm * 32 + mt * 16 + llo) * 264 + k0 + lhi * 8;
      ah[mt] = *(const bhalf8*)&Ah[ro];
      al[mt] = *(const bhalf8*)&Al[ro];
    }
#pragma unroll
    for (int nt = 0; nt < 4; nt++) {
      int ro = (wn * 64 + nt * 16 + llo) * 32 + lhi * 8;
      bh[nt] = *(const bhalf8*)&Bh[cur][ro];
      bl[nt] = *(const bhalf8*)&Bl[cur][ro];
    }
#pragma unroll
    for (int mt = 0; mt < 2; mt++)
#pragma unroll
      for (int nt = 0; nt < 4; nt++) {
        acc[mt][nt] = __builtin_amdgcn_mfma_f32_16x16x32_bf16(ah[mt], bh[nt], acc[mt][nt], 0, 0, 0);
        acc[mt][nt] = __builtin_amdgcn_mfma_f32_16x16x32_bf16(ah[mt], bl[nt], acc[mt][nt], 0, 0, 0);
        acc[mt][nt] = __builtin_amdgcn_mfma_f32_16x16x32_bf16(al[mt], bh[nt], acc[mt][nt], 0, 0, 0);
      }
    __syncthreads();
  }

  float a1v[4], a2v[4];
#pragma unroll
  for (int nt = 0; nt < 4; nt++) {
    int f = wn * 64 + nt * 16 + llo;
    a1v[nt] = a_g[f];
    a2v[nt] = a_g[256 + f];
  }

  const int b = (int)(r0 >> 11);
  const int jt_base = (int)((r0 & 2047) >> 5);

#pragma unroll
  for (int mt = 0; mt < 2; mt++) {
    float p1[4], p2[4];
#pragma unroll
    for (int reg = 0; reg < 4; reg++) {
      p1[reg] = acc[mt][0][reg] * a1v[0] + acc[mt][1][reg] * a1v[1] +
                acc[mt][2][reg] * a1v[2] + acc[mt][3][reg] * a1v[3];
      p2[reg] = acc[mt][0][reg] * a2v[0] + acc[mt][1][reg] * a2v[1] +
                acc[mt][2][reg] * a2v[2] + acc[mt][3][reg] * a2v[3];
    }
#pragma unroll
    for (int off = 1; off < 16; off <<= 1) {
#pragma unroll
      for (int reg = 0; reg < 4; reg++) {
        p1[reg] += __shfl_xor(p1[reg], off);
        p2[reg] += __shfl_xor(p2[reg], off);
      }
    }
    if (llo == 0) {
#pragma unroll
      for (int reg = 0; reg < 4; reg++) {
        int il = wm * 32 + mt * 16 + lhi * 4 + reg;
        atomicAdd(&s1red[il], p1[reg]);
        atomicAdd(&s2red[il], p2[reg]);
      }
    }
#pragma unroll
    for (int nt = 0; nt < 4; nt++) {
      int f = wn * 64 + nt * 16 + llo;
      int jt = jt_base + wm;
      ushort4 pk = (ushort4){f2bf(acc[mt][nt][0]), f2bf(acc[mt][nt][1]),
                             f2bf(acc[mt][nt][2]), f2bf(acc[mt][nt][3])};
      *(ushort4*)&WhPack[((long)((b * 64 + jt) * 256 + f)) * 32 + mt * 16 + lhi * 4] = pk;
    }
  }

  __syncthreads();
  if (t < 64) {
    s1[r0 + t] = s1red[t];
    s2[r0 + t] = s2red[t];
    float v = s2red[t];
#pragma unroll
    for (int o = 32; o; o >>= 1) v = fmaxf(v, __shfl_xor(v, o));
    if (t == 0) {
      unsigned int u = __float_as_uint(v);
      unsigned int key = (u & 0x80000000u) ? ~u : (u | 0x80000000u);
      atomicMax(s2maxEnc + b, key);
    }
  }
}

// ---------------------------------------------------------------------------
// K3 v5 (R6 structure + swizzle + deep pipeline + partial-drain barrier):
// - WhT bank-conflict-free: chunk (f,c) at slot f*4 + (c ^ ((f>>1)&3));
//   gld16 source is per-lane remapped, frag reads are 2-way (= free).
// - 4 WhT buffers, gld16 issued at distance 3, adj regs depth 4.
// - Loop barrier = s_waitcnt vmcnt(6) lgkmcnt(0) + raw s_barrier: tiles stay
//   in flight ACROSS the barrier (vmcnt(6) provably drains tile jt+1: it
//   always has >=7 newer loads). This is the AITER fine-grained-vmcnt pattern.
// grid (64, 8) x 512 thr; block 32 rows x 256 f; wave tile 16 x 64.
// LDS ~79 KB -> 2 blocks/CU.
// ---------------------------------------------------------------------------
__global__ __launch_bounds__(512, 4) void k3_attn(const unsigned short* __restrict__ WhPack,
                                                  const int* __restrict__ adj,
                                                  const float* __restrict__ s1g,
                                                  const float* __restrict__ s2g,
                                                  const unsigned int* __restrict__ s2maxEnc,
                                                  float* __restrict__ out) {
  const int t = threadIdx.x;
  const int i0 = blockIdx.x * 32;
  const int b = blockIdx.y;
  const long gr0 = (long)b * 2048 + i0;

  __shared__ float s2all[2048];            // 8 KB
  __shared__ unsigned short WhT[4][8192];  // 4 x 16 KB, swizzled
  __shared__ unsigned short P[2][1280];    // [i=32][j' pad 40]
  __shared__ float lvv[32];

  ((float4*)s2all)[t] = ((const float4*)(s2g + (long)b * 2048))[t];

  const int wave = t >> 6, lane = t & 63;
  const int wm = wave >> 2, wn = wave & 3;
  const int lhi = lane >> 4, llo = lane & 15;
  const int i_p = t >> 4;        // P row (0..31)
  const int jl0 = (t & 15) * 2;  // P j-local base

  const float s1i = s1g[gr0 + i_p];
  const unsigned int ek = s2maxEnc[b];
  const float s2max = (ek & 0x80000000u) ? __uint_as_float(ek & 0x7fffffffu)
                                         : __uint_as_float(~ek);
  const float xm = s1i + s2max;
  const float Mi = fmaxf(xm, ALPHA_LR * xm);  // valid softmax shift (upper bound)

  const int* aptr = adj + (gr0 + i_p) * 2048 + jl0;
  const unsigned short* tbase = WhPack + ((long)b * 64) * 8192;
  // swizzle: LDS slot s holds global chunk (f = s>>2, c = (s&3)^((s>>3)&3))
  const int laneoff = (lane >> 2) * 32 + (((lane & 3) ^ ((lane >> 3) & 3)) * 8);
  const int segoff = wave * 1024;  // + rep*512 (shorts)

  // prologue: async tiles 0..2; adj tiles 0..4 into regs
#pragma unroll
  for (int tile = 0; tile < 3; tile++)
#pragma unroll
    for (int rep = 0; rep < 2; rep++) {
      const int off = segoff + rep * 512;
      gld16(tbase + tile * 8192 + off + laneoff, &WhT[tile][off]);
    }
  const int2 aj0 = *(const int2*)aptr;
  int2 ajbuf[4];
#pragma unroll
  for (int q = 1; q <= 4; q++) ajbuf[q & 3] = *(const int2*)(aptr + q * 32);
  __syncthreads();  // s2all + tiles 0..2 landed (full drain, once)

  float lsum = 0.f;
  {  // P tile 0
    float x0 = s1i + s2all[jl0];
    float x1 = s1i + s2all[jl0 + 1];
    x0 = fmaxf(x0, ALPHA_LR * x0);
    x1 = fmaxf(x1, ALPHA_LR * x1);
    float e0 = (aj0.x > 0) ? __expf(x0 - Mi) : 0.f;
    float e1 = (aj0.y > 0) ? __expf(x1 - Mi) : 0.f;
    lsum = e0 + e1;
    *(unsigned int*)&P[0][i_p * 40 + jl0] = (unsigned)f2bf(e0) | ((unsigned)f2bf(e1) << 16);
  }
  __syncthreads();  // P[0] visible

  floatx4 acc[4];
#pragma unroll
  for (int nt = 0; nt < 4; nt++) acc[nt] = (floatx4){0.f, 0.f, 0.f, 0.f};

  // B frag base (swizzled): f = wn*64 + nt*16 + llo, chunk lhi
  const int baseB = (wn * 64 + llo) * 32 + ((lhi ^ ((llo >> 1) & 3)) * 8);
  const int aoff = (wm * 16 + llo) * 40 + lhi * 8;

  for (int jt = 0; jt < 64; jt++) {
    const int cur = jt & 3;
    // (1) issue tile jt+3 (distance-3 prefetch)
    if (jt < 61) {
      const int ld = (jt + 3) & 3;
      const long gb = (long)(jt + 3) * 8192;
#pragma unroll
      for (int rep = 0; rep < 2; rep++) {
        const int off = segoff + rep * 512;
        gld16(tbase + gb + off + laneoff, &WhT[ld][off]);
      }
    }
    // (2) P for tile jt+1; adj refill at depth 4
    if (jt < 63) {
      const int jtn = jt + 1;
      const int2 ajc = ajbuf[jtn & 3];
      if (jt < 59) ajbuf[(jt + 5) & 3] = *(const int2*)(aptr + (jt + 5) * 32);
      float x0 = s1i + s2all[jtn * 32 + jl0];
      float x1 = s1i + s2all[jtn * 32 + jl0 + 1];
      x0 = fmaxf(x0, ALPHA_LR * x0);
      x1 = fmaxf(x1, ALPHA_LR * x1);
      float e0 = (ajc.x > 0) ? __expf(x0 - Mi) : 0.f;
      float e1 = (ajc.y > 0) ? __expf(x1 - Mi) : 0.f;
      lsum += e0 + e1;
      *(unsigned int*)&P[jtn & 1][i_p * 40 + jl0] =
          (unsigned)f2bf(e0) | ((unsigned)f2bf(e1) << 16);
    }
    // (3) frags from current buffers + MFMA
    bhalf8 af = *(const bhalf8*)&P[jt & 1][aoff];
    bhalf8 bf[4];
#pragma unroll
    for (int nt = 0; nt < 4; nt++)
      bf[nt] = *(const bhalf8*)&WhT[cur][baseB + nt * 512];
#pragma unroll
    for (int nt = 0; nt < 4; nt++)
      acc[nt] = __builtin_amdgcn_mfma_f32_16x16x32_bf16(af, bf[nt], acc[nt], 0, 0, 0);
    // (4) partial-drain barrier: wait LDS ops + all-but-6-newest vmem, then
    // raw s_barrier — prefetched tiles stay in flight across it.
    __builtin_amdgcn_s_waitcnt(0x76);  // vmcnt(6) expcnt(7) lgkmcnt(0)
    __builtin_amdgcn_s_barrier();
  }

  // denominator: reduce lsum across the 16 lanes sharing row i_p
  lsum += __shfl_xor(lsum, 1);
  lsum += __shfl_xor(lsum, 2);
  lsum += __shfl_xor(lsum, 4);
  lsum += __shfl_xor(lsum, 8);
  if ((t & 15) == 0) lvv[i_p] = 1.f / fmaxf(lsum, 1e-35f);
  __syncthreads();

  // epilogue: normalize, ELU, store. C/D: row = lhi*4+reg, col = llo
#pragma unroll
  for (int nt = 0; nt < 4; nt++) {
#pragma unroll
    for (int reg = 0; reg < 4; reg++) {
      int il = wm * 16 + lhi * 4 + reg;
      int f = wn * 64 + nt * 16 + llo;
      float v = acc[nt][reg] * lvv[il];
      v = v > 0.f ? v : expm1f(v);
      out[(gr0 + il) * 256 + f] = v;
    }
  }
}

// ---------------------------------------------------------------------------
extern "C" void kernel_launch(void* const* d_in, const int* in_sizes, int n_in,
                              void* d_out, int out_size, void* d_ws, size_t ws_size,
                              hipStream_t stream) {
  const float* h = (const float*)d_in[0];
  const int* adj = (const int*)d_in[1];
  const float* W = (const float*)d_in[2];
  const float* a = (const float*)d_in[3];
  float* out = (float*)d_out;

  char* ws = (char*)d_ws;
  unsigned short* WhPack = (unsigned short*)ws;            //  8,388,608 B
  unsigned short* WThi = (unsigned short*)(ws + 8388608);  //    131,072 B
  unsigned short* WTlo = (unsigned short*)(ws + 8519680);  //    131,072 B
  float* s1 = (float*)(ws + 8650752);                      //     65,536 B
  float* s2 = (float*)(ws + 8716288);                      //     65,536 B
  unsigned int* s2maxEnc = (unsigned int*)(ws + 8781824);  //         32 B

  hipLaunchKernelGGL(k0w_split, dim3(16, 16), dim3(16, 16), 0, stream, W, WThi, WTlo, s2maxEnc);
  hipLaunchKernelGGL(k1_mfma, dim3(256), dim3(512), 0, stream, h, WThi, WTlo, a,
                     WhPack, s1, s2, s2maxEnc);
  hipLaunchKernelGGL(k3_attn, dim3(64, 8), dim3(512), 0, stream, WhPack, adj,
                     s1, s2, s2maxEnc, out);
}